// Round 6
// baseline (4958.839 us; speedup 1.0000x reference)
//
#include <hip/hip_runtime.h>
#include <stdint.h>

#define NBATCH 32
#define NPTS   65536
#define MCENT  2048
#define BPB    8                 // blocks per batch
#define THREADS 1024
#define CHUNK  (NPTS / BPB)      // 8192 points per block
#define WPT    (CHUNK / THREADS) // 8 points per thread
#define NWAVE  (THREADS / 64)    // 16 waves
#define GPW    2                 // groups (half-waves) per wave
#define NGRP   (NWAVE * GPW)     // 32 groups per block
#define TMAX   64                // max centers selected per sync round

typedef unsigned long long u64;
typedef uint32_t u32;

static __device__ __forceinline__ u32 fbits(float f) { union { float f; u32 u; } c; c.f = f; return c.u; }
static __device__ __forceinline__ float bitsf(u32 u) { union { u32 u; float f; } c; c.u = u; return c.f; }

// wave-wide max of nonneg u32 via DPP row reduce (proven R4/R5);
// bound_ctrl=true -> invalid sources read 0 (identity for nonneg max).
static __device__ __forceinline__ u32 wave_max_u32(u32 v) {
#define STEP(CTRL) { const u32 o = (u32)__builtin_amdgcn_update_dpp(0, (int)v, CTRL, 0xF, 0xF, true); v = o > v ? o : v; }
    STEP(0x111) // row_shr:1
    STEP(0x112) // row_shr:2
    STEP(0x114) // row_shr:4
    STEP(0x118) // row_shr:8
    STEP(0x142) // row_bcast15
    STEP(0x143) // row_bcast31
#undef STEP
    return (u32)__builtin_amdgcn_readlane((int)v, 63);
}

// Multi-step FPS with a published candidate pool (proven R5 protocol),
// now with a BARRIER-FREE round loop: wave 0 broadcasts each selected
// winner through tagged LDS slots the moment it is found; waves 1..15
// consume winners incrementally (Phase A overlapped with pool-FPS).
//
// Global pool protocol (unchanged, proven R2..R5):
//   word = val_bits[63:32] | (idx^0xFFFF)[31:16] | sync_tag[15:0]
//   Tags: poison 0xAA.. -> 0xAAAA, zero -> 0; s in [1,2047] never aliases.
//   Parity reuse safe (now via transitive ordering): publish(X,s) happens
//   after X consumed round s-1 winners, which happens after X.wave0's
//   round s-1 poll completed, which is after every peer Y published s-1,
//   which is after Y consumed s-2, i.e. after Y banked its reads of X's
//   s-2 words. So overwriting parity-(s&1) words at round s is safe.
//
// Intra-block LDS winner protocol (new):
//   slot tt: {wsx,wsy,wsz}[tt] then threadfence_block then wstag[tt]=s.
//   After the last winner: threadfence_block then wtn=(s<<8)|tn.
//   Consumers accept slot tt only when wstag[tt]==s-1 (their round lags
//   the producer tag by construction); stale tags from older rounds and
//   the 0xFFFFFFFF sentinel can never match. LDS ds ops complete in
//   order per wave, and the producer fences between data and tag, so an
//   accepted tag implies valid data. No __syncthreads in the main loop.
//
// Exactness: winner sequence, distance chain (subs, then
// fma(dz,dz, fma(dx,dx, mul(dy,dy))), chronological fminf), tau rule
// (accept iff value strictly > max of group TOPK-th values) and
// first-occurrence tie-breaks are bit-identical to the verified R5.

template<int TOPK>
__global__ __launch_bounds__(THREADS, 1) void fps_kernel(
    const float* __restrict__ xyz,      // [NBATCH, NPTS, 3] fp32
    float* __restrict__ out,            // [NBATCH, MCENT, 3] fp32
    u64* __restrict__ slots)
{
    constexpr int POOLW = BPB * NGRP * TOPK;   // words per batch per parity
    constexpr int WPL   = POOLW / 64;          // words per lane (wave 0)

    const int t = threadIdx.x;
    const int b = blockIdx.x >> 3;   // batch (proven mapping)
    const int j = blockIdx.x & 7;    // block-within-batch
    const float* base = xyz + (size_t)b * NPTS * 3;
    const int p0 = j * CHUNK;
    const int wave = t >> 6;
    const int lane = t & 63;

    // coords + running min-dist live in registers
    float px[WPT], py[WPT], pz[WPT], pd[WPT];
#pragma unroll
    for (int q = 0; q < WPT; ++q) {
        const int p = p0 + q * THREADS + t;
        px[q] = base[(size_t)p * 3 + 0];
        py[q] = base[(size_t)p * 3 + 1];
        pz[q] = base[(size_t)p * 3 + 2];
        pd[q] = 1e10f;
    }

    // tagged LDS winner slots
    __shared__ volatile float wsx[TMAX], wsy[TMAX], wsz[TMAX];
    __shared__ volatile u32   wstag[TMAX];
    __shared__ volatile u32   wtn;     // (round<<8) | count

    if (t < TMAX) wstag[t] = 0xFFFFFFFFu;  // sentinel: matches no round
    if (t == 0) {
        wsx[0] = base[0]; wsy[0] = base[1]; wsz[0] = base[2];
        wstag[0] = 0u;                 // "round 0" winner = initial center
        wtn = (0u << 8) | 1u;
        if (j == 0) {
            float* o = out + (size_t)b * MCENT * 3;
            o[0] = base[0]; o[1] = base[1]; o[2] = base[2];
        }
    }
    __syncthreads();   // the ONLY barrier (init visibility)

    int C;
    if (wave == 0) {
        // wave 0 applies the initial center directly (not via LDS spin)
        const float cx = base[0], cy = base[1], cz = base[2];
#pragma unroll
        for (int q = 0; q < WPT; ++q) {
            const float dx = __fsub_rn(px[q], cx);
            const float dy = __fsub_rn(py[q], cy);
            const float dz = __fsub_rn(pz[q], cz);
            const float s2 = __fmaf_rn(dz, dz,
                             __fmaf_rn(dx, dx,
                             __fmul_rn(dy, dy)));
            pd[q] = fminf(pd[q], s2);
        }
        C = 1;
    } else {
        C = 0;
    }

    for (int s = 1; ; ++s) {
        if (wave != 0) {
            // ---- consume winners of round s-1 incrementally from LDS ----
            int tt = 0, tn = -1;
            while (tn < 0 || tt < tn) {
                const u32 tg = wstag[tt];
                if (tg == (u32)(s - 1)) {
                    const float cx = wsx[tt], cy = wsy[tt], cz = wsz[tt];
#pragma unroll
                    for (int q = 0; q < WPT; ++q) {
                        const float dx = __fsub_rn(px[q], cx);
                        const float dy = __fsub_rn(py[q], cy);
                        const float dz = __fsub_rn(pz[q], cz);
                        const float s2 = __fmaf_rn(dz, dz,
                                         __fmaf_rn(dx, dx,
                                         __fmul_rn(dy, dy)));
                        pd[q] = fminf(pd[q], s2);
                    }
                    ++tt;
                } else if (tn < 0) {
                    const u32 wd = wtn;
                    if ((wd >> 8) == (u32)(s - 1)) tn = (int)(wd & 0xFFu);
                }
            }
            C += tt;
        }
        if (C >= MCENT) break;     // uniform exit point for every wave

        // ---- per-lane top-TOPK keys over its 8 points (sorted insert) ----
        u64 k1 = 0, k2 = 0, k3 = 0;
#pragma unroll
        for (int q = 0; q < WPT; ++q) {
            const u64 kk = ((u64)fbits(pd[q]) << 16)
                         | (u64)(0xFFFFu ^ (u32)(p0 + q * THREADS + t));
            if (kk > k1)      { k3 = k2; k2 = k1; k1 = kk; }
            else if (kk > k2) { k3 = k2; k2 = kk; }
            else if (kk > k3) { k3 = kk; }
        }
        // ---- half-wave top-TOPK butterfly (5 xor levels, 32 lanes) ----
#pragma unroll
        for (int m = 1; m <= 16; m <<= 1) {
            const u64 o1 = __shfl_xor(k1, m);
            const u64 o2 = __shfl_xor(k2, m);
            if constexpr (TOPK == 2) {
                if (o1 > k1) { k2 = (k1 > o2) ? k1 : o2; k1 = o1; }
                else         { k2 = (k2 > o1) ? k2 : o1; }
            } else {
                const u64 o3 = __shfl_xor(k3, m);
                u64 m1, m2, m3;
                if (o1 > k1) {
                    m1 = o1;
                    if (o2 > k1) { m2 = o2; m3 = (o3 > k1) ? o3 : k1; }
                    else         { m2 = k1; m3 = (o2 > k2) ? o2 : k2; }
                } else {
                    m1 = k1;
                    if (o1 > k2) { m2 = o1; m3 = (o2 > k2) ? o2 : k2; }
                    else         { m2 = k2; m3 = (o1 > k3) ? o1 : k3; }
                }
                k1 = m1; k2 = m2; k3 = m3;
            }
        }

        u64* const bb = slots + ((size_t)(s & 1) * NBATCH + b) * POOLW;
        const u32 tag = (u32)s & 0xFFFFu;

        // ---- publish: first lane of each half-wave stores TOPK words ----
        if ((lane & 31) == 0) {
            const int g = wave * GPW + (lane >> 5);     // group id 0..31
            u64* const gw = &bb[j * (NGRP * TOPK) + g * TOPK];
            __hip_atomic_store(&gw[0], (k1 << 16) | tag,
                               __ATOMIC_RELAXED, __HIP_MEMORY_SCOPE_AGENT);
            __hip_atomic_store(&gw[1], (k2 << 16) | tag,
                               __ATOMIC_RELAXED, __HIP_MEMORY_SCOPE_AGENT);
            if constexpr (TOPK == 3)
                __hip_atomic_store(&gw[2], (k3 << 16) | tag,
                                   __ATOMIC_RELAXED, __HIP_MEMORY_SCOPE_AGENT);
        }
        // waves 1..15 loop straight to the next consume; wave 0 polls.

        if (wave == 0) {
            // ---- poll: WPL coalesced words/lane until all carry tag s ----
            u64 w[WPL]; int ok;
            do {
#pragma unroll
                for (int r = 0; r < WPL; ++r)
                    w[r] = __hip_atomic_load(&bb[lane + 64 * r],
                                             __ATOMIC_RELAXED, __HIP_MEMORY_SCOPE_AGENT);
                ok = 1;
#pragma unroll
                for (int r = 0; r < WPL; ++r)
                    ok &= ((u32)(w[r] & 0xFFFFull) == tag);
            } while (!__all(ok));

            // ---- unpack pool: split (val, inv-idx) + gather coords ----
            u32 pv[WPL], pi[WPL];
            float ex[WPL], ey[WPL], ez[WPL];
#pragma unroll
            for (int r = 0; r < WPL; ++r) {
                pv[r] = (u32)(w[r] >> 32);
                pi[r] = ((u32)w[r] >> 16) & 0xFFFFu;
                const int gi = (int)(0xFFFFu ^ pi[r]);   // global point idx
                ex[r] = base[(size_t)gi * 3 + 0];
                ey[r] = base[(size_t)gi * 3 + 1];
                ez[r] = base[(size_t)gi * 3 + 2];
            }

            // tau = max over group-LAST (TOPK-th) entries. Word index is
            // lane + 64*r -> rank = (lane%TOPK + (64%TOPK)*r) % TOPK.
            u32 tl = 0;
#pragma unroll
            for (int r = 0; r < WPL; ++r) {
                const int rank = ((lane % TOPK) + (64 % TOPK) * r) % TOPK;
                if (rank == TOPK - 1) tl = pv[r] > tl ? pv[r] : tl;
            }
            const u32 tauv = wave_max_u32(tl);

            // ---- pool-FPS: exact multi-step selection + live broadcast ----
            int tc = 0;
            while (1) {
                u32 lv = 0;
#pragma unroll
                for (int r = 0; r < WPL; ++r) lv = pv[r] > lv ? pv[r] : lv;
                const u32 vmax = wave_max_u32(lv);
                // step >=2 valid only if winner VALUE strictly beats tau
                if (tc > 0 && vmax <= tauv) break;

                // per-lane best inv among entries matching vmax (0 = none)
                u32 ic = 0;
#pragma unroll
                for (int r = 0; r < WPL; ++r)
                    ic = (pv[r] == vmax && pi[r] + 1u > ic) ? pi[r] + 1u : ic;
                const u64 bal = __ballot(ic != 0);
                u32 winv; int ol;
                if (__popcll(bal) == 1) {
                    ol = (int)__ffsll((long long)bal) - 1;
                    winv = __shfl(ic, ol) - 1u;
                } else {
                    winv = wave_max_u32(ic) - 1u;
                    int m = 0;
#pragma unroll
                    for (int r = 0; r < WPL; ++r)
                        m |= (pv[r] == vmax) & (pi[r] == winv);
                    ol = (int)__ffsll((long long)__ballot(m)) - 1;
                }

                // owner entry -> winner coords to all lanes
                float sx = 0.f, sy = 0.f, sz = 0.f;
#pragma unroll
                for (int r = 0; r < WPL; ++r) {
                    const int m = (pv[r] == vmax) & (pi[r] == winv);
                    sx = m ? ex[r] : sx;
                    sy = m ? ey[r] : sy;
                    sz = m ? ez[r] : sz;
                }
                const float wx = __shfl(sx, ol);
                const float wy = __shfl(sy, ol);
                const float wz = __shfl(sz, ol);

                // live broadcast: slot data, fence, tag
                if (lane == 0) {
                    wsx[tc] = wx; wsy[tc] = wy; wsz[tc] = wz;
                    __threadfence_block();
                    wstag[tc] = (u32)s;
                    if (j == 0) {
                        float* o = out + ((size_t)b * MCENT + (C + tc)) * 3;
                        o[0] = wx; o[1] = wy; o[2] = wz;
                    }
                }

                // inline update of wave 0's own points (fills DPP stalls)
#pragma unroll
                for (int q = 0; q < WPT; ++q) {
                    const float dx = __fsub_rn(px[q], wx);
                    const float dy = __fsub_rn(py[q], wy);
                    const float dz = __fsub_rn(pz[q], wz);
                    const float s2 = __fmaf_rn(dz, dz,
                                     __fmaf_rn(dx, dx,
                                     __fmul_rn(dy, dy)));
                    pd[q] = fminf(pd[q], s2);
                }

                ++tc;
                if (C + tc >= MCENT || tc >= TMAX) break;

                // min-update all pool entries vs winner (bit-exact chain)
#pragma unroll
                for (int r = 0; r < WPL; ++r) {
                    const float dx = __fsub_rn(ex[r], wx);
                    const float dy = __fsub_rn(ey[r], wy);
                    const float dz = __fsub_rn(ez[r], wz);
                    const float s2 = __fmaf_rn(dz, dz,
                                     __fmaf_rn(dx, dx,
                                     __fmul_rn(dy, dy)));
                    pv[r] = fbits(fminf(bitsf(pv[r]), s2));
                }
            }
            if (lane == 0) {
                __threadfence_block();
                wtn = ((u32)s << 8) | (u32)tc;   // count, tagged with round
            }
            C += tc;
        }
    }
}

extern "C" void kernel_launch(void* const* d_in, const int* in_sizes, int n_in,
                              void* d_out, int out_size, void* d_ws, size_t ws_size,
                              hipStream_t stream) {
    const float* xyz = (const float*)d_in[0];
    float* out = (float*)d_out;
    u64* slots = (u64*)d_ws;

    // top-3 pool needs 2 parity x 32 batch x 768 words x 8 B = 384 KiB
    const size_t need3 = 2ull * NBATCH * (BPB * NGRP * 3) * sizeof(u64);
    if (ws_size >= need3) {
        fps_kernel<3><<<dim3(NBATCH * BPB), dim3(THREADS), 0, stream>>>(xyz, out, slots);
    } else {
        // proven-size fallback (256 KiB)
        fps_kernel<2><<<dim3(NBATCH * BPB), dim3(THREADS), 0, stream>>>(xyz, out, slots);
    }
}

// Round 7
// 2223.996 us; speedup vs baseline: 2.2297x; 2.2297x over previous
//
#include <hip/hip_runtime.h>
#include <stdint.h>

#define NBATCH 32
#define NPTS   65536
#define MCENT  2048
#define BPB    16                // blocks per batch (2 blocks/CU for TLP)
#define THREADS 512
#define CHUNK  (NPTS / BPB)      // 4096 points per block
#define WPT    (CHUNK / THREADS) // 8 points per thread
#define NWAVE  (THREADS / 64)    // 8 waves
#define GPW    2                 // groups (half-waves) per wave
#define NGRP   (NWAVE * GPW)     // 16 groups per block (256 pts each)
#define TMAX   64                // max centers selected per sync round

typedef unsigned long long u64;
typedef uint32_t u32;

static __device__ __forceinline__ u32 fbits(float f) { union { float f; u32 u; } c; c.f = f; return c.u; }
static __device__ __forceinline__ float bitsf(u32 u) { union { u32 u; float f; } c; c.u = u; return c.f; }

// wave-wide max of nonneg u32 via DPP row reduce (proven R4/R5);
// bound_ctrl=true -> invalid sources read 0 (identity for nonneg max).
static __device__ __forceinline__ u32 wave_max_u32(u32 v) {
#define STEP(CTRL) { const u32 o = (u32)__builtin_amdgcn_update_dpp(0, (int)v, CTRL, 0xF, 0xF, true); v = o > v ? o : v; }
    STEP(0x111) // row_shr:1
    STEP(0x112) // row_shr:2
    STEP(0x114) // row_shr:4
    STEP(0x118) // row_shr:8
    STEP(0x142) // row_bcast15
    STEP(0x143) // row_bcast31
#undef STEP
    return (u32)__builtin_amdgcn_readlane((int)v, 63);
}

// Multi-step FPS with a published candidate pool. Structure = proven R5
// (single loop-top barrier per round; barrier-free R6 variant REGRESSED
// 2.4x: spinning waves stole issue slots from wave 0's serial pool-FPS —
// s_barrier parks waves for free, keep it).
//
// This revision changes ONLY the block topology: 512 blocks x 512 threads
// (2 blocks/CU). While one block's wave 0 polls the global pool (its
// siblings parked at the barrier), the co-resident block's waves keep
// issuing Phase A — sync latency hidden by TLP. The batch pool is
// isomorphic to R5: 256 groups of 256 points per batch (16 half-wave
// groups x 16 blocks), TOPK entries per group.
//
// Pool protocol (d_ws = 2 parity x NBATCH x POOLW u64 words; proven):
//   word = val_bits[63:32] | (idx^0xFFFF)[31:16] | sync_tag[15:0]
//   key order (val desc, idx asc) == jnp.argmax first-occurrence semantics.
//   Tags: poison 0xAA.. -> 0xAAAA, zero -> 0; s in [1,2047] never aliases.
//   Parity reuse safe: a block overwrites parity-p words at round s+2 only
//   after observing all round-s+1 tags; a peer publishes s+1 only after its
//   round-s poll banked all round-s words in registers.
//
// Exactness (every block replicates the identical pool computation):
//   step 1: pool holds every group's max -> pool argmax == global argmax.
//   step t>=2: any point NOT in the pool is <= its group's published
//   TOPK-th value <= tau = max over groups of TOPK-th values (true dists
//   only decrease). Accept a winner iff its VALUE strictly > tau (hidden
//   points can then neither beat nor tie it); else bail and re-sync.
//   All distance math is the verified bit-exact chain: subs, then
//   fma(dz,dz, fma(dx,dx, mul(dy,dy))), chronological fminf order.

template<int TOPK>
__global__ __launch_bounds__(THREADS, 4) void fps_kernel(
    const float* __restrict__ xyz,      // [NBATCH, NPTS, 3] fp32
    float* __restrict__ out,            // [NBATCH, MCENT, 3] fp32
    u64* __restrict__ slots)
{
    constexpr int POOLW = BPB * NGRP * TOPK;   // words per batch per parity
    constexpr int WPL   = POOLW / 64;          // words per lane (wave 0)

    const int t = threadIdx.x;
    const int b = blockIdx.x >> 4;   // batch
    const int j = blockIdx.x & 15;   // block-within-batch
    const float* base = xyz + (size_t)b * NPTS * 3;
    const int p0 = j * CHUNK;
    const int wave = t >> 6;
    const int lane = t & 63;

    // coords + running min-dist live in registers
    float px[WPT], py[WPT], pz[WPT], pd[WPT];
#pragma unroll
    for (int q = 0; q < WPT; ++q) {
        const int p = p0 + q * THREADS + t;
        px[q] = base[(size_t)p * 3 + 0];
        py[q] = base[(size_t)p * 3 + 1];
        pz[q] = base[(size_t)p * 3 + 2];
        pd[q] = 1e10f;
    }

    __shared__ float wcx[TMAX], wcy[TMAX], wcz[TMAX]; // winners of last round
    __shared__ int   wcnt;

    if (t == 0) {
        const float cx = base[0], cy = base[1], cz = base[2];
        wcx[0] = cx; wcy[0] = cy; wcz[0] = cz; wcnt = 1;
        if (j == 0) {
            float* o = out + (size_t)b * MCENT * 3;
            o[0] = cx; o[1] = cy; o[2] = cz;
        }
    }

    int C = 0;  // centers accounted (uniform across all blocks)
    for (int s = 1; ; ++s) {
        __syncthreads();                 // wcnt / wc* of previous round valid
        const int tn = wcnt;
        C += tn;
        if (C >= MCENT) break;

        // ---- Phase A: update running min-dist vs the tn new centers ----
        for (int tt = 0; tt < tn; ++tt) {
            const float cx = wcx[tt], cy = wcy[tt], cz = wcz[tt];
#pragma unroll
            for (int q = 0; q < WPT; ++q) {
                const float dx = __fsub_rn(px[q], cx);
                const float dy = __fsub_rn(py[q], cy);
                const float dz = __fsub_rn(pz[q], cz);
                const float s2 = __fmaf_rn(dz, dz,
                                 __fmaf_rn(dx, dx,
                                 __fmul_rn(dy, dy)));
                pd[q] = fminf(pd[q], s2);
            }
        }

        // ---- per-lane top-TOPK keys over its 8 points (sorted insert) ----
        u64 k1 = 0, k2 = 0, k3 = 0;
#pragma unroll
        for (int q = 0; q < WPT; ++q) {
            const u64 kk = ((u64)fbits(pd[q]) << 16)
                         | (u64)(0xFFFFu ^ (u32)(p0 + q * THREADS + t));
            if (kk > k1)      { k3 = k2; k2 = k1; k1 = kk; }
            else if (kk > k2) { k3 = k2; k2 = kk; }
            else if (kk > k3) { k3 = kk; }
        }
        // ---- half-wave top-TOPK butterfly (5 xor levels, 32 lanes) ----
#pragma unroll
        for (int m = 1; m <= 16; m <<= 1) {
            const u64 o1 = __shfl_xor(k1, m);
            const u64 o2 = __shfl_xor(k2, m);
            if constexpr (TOPK == 2) {
                if (o1 > k1) { k2 = (k1 > o2) ? k1 : o2; k1 = o1; }
                else         { k2 = (k2 > o1) ? k2 : o1; }
            } else {
                const u64 o3 = __shfl_xor(k3, m);
                // merge sorted triples (k1>=k2>=k3), (o1>=o2>=o3) -> top-3
                u64 m1, m2, m3;
                if (o1 > k1) {
                    m1 = o1;
                    if (o2 > k1) { m2 = o2; m3 = (o3 > k1) ? o3 : k1; }
                    else         { m2 = k1; m3 = (o2 > k2) ? o2 : k2; }
                } else {
                    m1 = k1;
                    if (o1 > k2) { m2 = o1; m3 = (o2 > k2) ? o2 : k2; }
                    else         { m2 = k2; m3 = (o1 > k3) ? o1 : k3; }
                }
                k1 = m1; k2 = m2; k3 = m3;
            }
        }

        u64* const bb = slots + ((size_t)(s & 1) * NBATCH + b) * POOLW;
        const u32 tag = (u32)s & 0xFFFFu;

        // ---- publish: first lane of each half-wave stores TOPK words ----
        if ((lane & 31) == 0) {
            const int g = wave * GPW + (lane >> 5);     // group id 0..NGRP-1
            u64* const gw = &bb[j * (NGRP * TOPK) + g * TOPK];
            __hip_atomic_store(&gw[0], (k1 << 16) | tag,
                               __ATOMIC_RELAXED, __HIP_MEMORY_SCOPE_AGENT);
            __hip_atomic_store(&gw[1], (k2 << 16) | tag,
                               __ATOMIC_RELAXED, __HIP_MEMORY_SCOPE_AGENT);
            if constexpr (TOPK == 3)
                __hip_atomic_store(&gw[2], (k3 << 16) | tag,
                                   __ATOMIC_RELAXED, __HIP_MEMORY_SCOPE_AGENT);
        }
        // waves 1.. park at the loop-top barrier; wave 0 polls.

        if (wave == 0) {
            // ---- poll: WPL coalesced words/lane until all carry tag s ----
            u64 w[WPL]; int ok;
            do {
#pragma unroll
                for (int r = 0; r < WPL; ++r)
                    w[r] = __hip_atomic_load(&bb[lane + 64 * r],
                                             __ATOMIC_RELAXED, __HIP_MEMORY_SCOPE_AGENT);
                ok = 1;
#pragma unroll
                for (int r = 0; r < WPL; ++r)
                    ok &= ((u32)(w[r] & 0xFFFFull) == tag);
            } while (!__all(ok));

            // ---- unpack pool: split (val, inv-idx) + gather coords ----
            u32 pv[WPL], pi[WPL];
            float ex[WPL], ey[WPL], ez[WPL];
#pragma unroll
            for (int r = 0; r < WPL; ++r) {
                pv[r] = (u32)(w[r] >> 32);
                pi[r] = ((u32)w[r] >> 16) & 0xFFFFu;
                const int gi = (int)(0xFFFFu ^ pi[r]);   // global point idx
                ex[r] = base[(size_t)gi * 3 + 0];
                ey[r] = base[(size_t)gi * 3 + 1];
                ez[r] = base[(size_t)gi * 3 + 2];
            }

            // tau = max over group-LAST (TOPK-th) entries. Word index is
            // lane + 64*r -> rank = (lane%TOPK + (64%TOPK)*r) % TOPK.
            u32 tl = 0;
#pragma unroll
            for (int r = 0; r < WPL; ++r) {
                const int rank = ((lane % TOPK) + (64 % TOPK) * r) % TOPK;
                if (rank == TOPK - 1) tl = pv[r] > tl ? pv[r] : tl;
            }
            const u32 tauv = wave_max_u32(tl);

            // ---- pool-FPS: exact multi-step selection ----
            int tc = 0;
            while (1) {
                u32 lv = 0;
#pragma unroll
                for (int r = 0; r < WPL; ++r) lv = pv[r] > lv ? pv[r] : lv;
                const u32 vmax = wave_max_u32(lv);
                // step >=2 valid only if winner VALUE strictly beats tau
                if (tc > 0 && vmax <= tauv) break;

                // per-lane best inv among entries matching vmax (0 = none)
                u32 ic = 0;
#pragma unroll
                for (int r = 0; r < WPL; ++r)
                    ic = (pv[r] == vmax && pi[r] + 1u > ic) ? pi[r] + 1u : ic;
                const u64 bal = __ballot(ic != 0);
                u32 winv; int ol;
                if (__popcll(bal) == 1) {
                    // single owner lane: local tie-break already in ic
                    ol = (int)__ffsll((long long)bal) - 1;
                    winv = __shfl(ic, ol) - 1u;
                } else {
                    // exact cross-lane tie-break: smallest global idx
                    winv = wave_max_u32(ic) - 1u;
                    int m = 0;
#pragma unroll
                    for (int r = 0; r < WPL; ++r)
                        m |= (pv[r] == vmax) & (pi[r] == winv);
                    ol = (int)__ffsll((long long)__ballot(m)) - 1;
                }

                // owner entry -> winner coords to all lanes
                float sx = 0.f, sy = 0.f, sz = 0.f;
#pragma unroll
                for (int r = 0; r < WPL; ++r) {
                    const int m = (pv[r] == vmax) & (pi[r] == winv);
                    sx = m ? ex[r] : sx;
                    sy = m ? ey[r] : sy;
                    sz = m ? ez[r] : sz;
                }
                const float wx = __shfl(sx, ol);
                const float wy = __shfl(sy, ol);
                const float wz = __shfl(sz, ol);

                if (lane == 0) {
                    wcx[tc] = wx; wcy[tc] = wy; wcz[tc] = wz;
                    if (j == 0) {
                        float* o = out + ((size_t)b * MCENT + (C + tc)) * 3;
                        o[0] = wx; o[1] = wy; o[2] = wz;
                    }
                }
                ++tc;
                if (C + tc >= MCENT || tc >= TMAX) break;

                // min-update all entries vs winner (bit-exact chain);
                // winner's own entry sinks to 0 automatically
#pragma unroll
                for (int r = 0; r < WPL; ++r) {
                    const float dx = __fsub_rn(ex[r], wx);
                    const float dy = __fsub_rn(ey[r], wy);
                    const float dz = __fsub_rn(ez[r], wz);
                    const float s2 = __fmaf_rn(dz, dz,
                                     __fmaf_rn(dx, dx,
                                     __fmul_rn(dy, dy)));
                    pv[r] = fbits(fminf(bitsf(pv[r]), s2));
                }
            }
            if (lane == 0) wcnt = tc;
        }
    }
}

extern "C" void kernel_launch(void* const* d_in, const int* in_sizes, int n_in,
                              void* d_out, int out_size, void* d_ws, size_t ws_size,
                              hipStream_t stream) {
    const float* xyz = (const float*)d_in[0];
    float* out = (float*)d_out;
    u64* slots = (u64*)d_ws;

    // top-3 pool needs 2 parity x 32 batch x 768 words x 8 B = 384 KiB
    const size_t need3 = 2ull * NBATCH * (BPB * NGRP * 3) * sizeof(u64);
    if (ws_size >= need3) {
        fps_kernel<3><<<dim3(NBATCH * BPB), dim3(THREADS), 0, stream>>>(xyz, out, slots);
    } else {
        // TOPK=2 fallback (256 KiB)
        fps_kernel<2><<<dim3(NBATCH * BPB), dim3(THREADS), 0, stream>>>(xyz, out, slots);
    }
}